// Round 2
// baseline (90.786 us; speedup 1.0000x reference)
//
#include <hip/hip_runtime.h>

#define BB 16
#define CC 256
#define TT 512
#define CSPLIT 16            // c-chunks per batch
#define CCHUNK (CC / CSPLIT) // 16 channels per block
#define FTILE 1024           // frames per block (256 threads * 4)

// Phase 1: per-batch inclusive scan of durations + scatter of frame->phoneme idx.
__global__ __launch_bounds__(TT) void lr_scan_kernel(
    const int* __restrict__ dur,      // [B, T]
    int* __restrict__ ws_mel,         // [B]
    int* __restrict__ ws_idx,         // [B, L]
    float* __restrict__ out_mel,      // d_out + B*C*L, [B]
    int L)
{
    __shared__ int wsum[TT / 64];
    const int b = blockIdx.x;
    const int t = threadIdx.x;

    int d = dur[b * TT + t];
    if (d < 0) d = 0;

    // inclusive scan within the 64-lane wave (no barriers)
    int v = d;
    #pragma unroll
    for (int off = 1; off < 64; off <<= 1) {
        int o = __shfl_up(v, off, 64);
        if ((t & 63) >= off) v += o;
    }
    const int wid = t >> 6;
    if ((t & 63) == 63) wsum[wid] = v;
    __syncthreads();

    int woff = 0;
    #pragma unroll
    for (int w = 0; w < TT / 64; ++w)
        if (w < wid) woff += wsum[w];

    const int cum = v + woff;          // inclusive cumsum
    const int start = cum - d;

    int* idx = ws_idx + (size_t)b * L;
    for (int f = start; f < cum; ++f) idx[f] = t;

    if (t == TT - 1) {
        ws_mel[b] = cum;
        out_mel[b] = (float)cum;       // mel_len emitted as float32
    }
}

// Phase 2: gather + zero-fill. Each block: one b, FTILE frames, CCHUNK channels.
// idx loaded ONCE per thread (int4), reused across the channel loop.
__global__ __launch_bounds__(256) void lr_gather_kernel(
    const float* __restrict__ x,      // [B, C, T]
    const int* __restrict__ ws_mel,   // [B]
    const int* __restrict__ ws_idx,   // [B, L]
    float* __restrict__ out,          // [B, C, L]
    int L)
{
    const int b  = blockIdx.z;
    const int c0 = blockIdx.y * CCHUNK;
    const int f0 = blockIdx.x * FTILE + threadIdx.x * 4;
    if (f0 >= L) return;

    const int ml = ws_mel[b];
    const int* __restrict__ idxp = ws_idx + (size_t)b * L;
    const float* __restrict__ xb = x + ((size_t)b * CC + c0) * TT;
    float* __restrict__ ob = out + ((size_t)b * CC + c0) * (size_t)L;

    if (((L & 3) == 0) && (f0 + 3 < L)) {
        // fast path: aligned float4 stores, idx as one int4
        const int4 id4 = *(const int4*)(idxp + f0);
        const bool m0 = (f0 + 0) < ml;
        const bool m1 = (f0 + 1) < ml;
        const bool m2 = (f0 + 2) < ml;
        const bool m3 = (f0 + 3) < ml;
        #pragma unroll
        for (int cc = 0; cc < CCHUNK; ++cc) {
            const float* __restrict__ xr = xb + (size_t)cc * TT;
            float4 v;
            v.x = m0 ? xr[id4.x] : 0.0f;
            v.y = m1 ? xr[id4.y] : 0.0f;
            v.z = m2 ? xr[id4.z] : 0.0f;
            v.w = m3 ? xr[id4.w] : 0.0f;
            *(float4*)(ob + (size_t)cc * L + f0) = v;
        }
    } else {
        const int fend = (f0 + 4 < L) ? (f0 + 4) : L;
        for (int cc = 0; cc < CCHUNK; ++cc) {
            for (int f = f0; f < fend; ++f) {
                float v = 0.0f;
                if (f < ml) v = xb[(size_t)cc * TT + idxp[f]];
                ob[(size_t)cc * L + f] = v;
            }
        }
    }
}

extern "C" void kernel_launch(void* const* d_in, const int* in_sizes, int n_in,
                              void* d_out, int out_size, void* d_ws, size_t ws_size,
                              hipStream_t stream)
{
    const float* x  = (const float*)d_in[0];
    const int* dur  = (const int*)d_in[1];
    float* out      = (float*)d_out;

    // out = [B, C, L] floats ++ mel_len[B]  =>  L = (out_size - B) / (B*C)
    const int L = (out_size - BB) / (BB * CC);

    int* ws_mel = (int*)d_ws;        // B ints
    int* ws_idx = ws_mel + BB;       // B*L ints (ws_idx 16B-aligned: 16 ints offset)
    float* out_mel = out + (size_t)BB * CC * L;

    lr_scan_kernel<<<BB, TT, 0, stream>>>(dur, ws_mel, ws_idx, out_mel, L);

    dim3 grid((L + FTILE - 1) / FTILE, CSPLIT, BB);
    lr_gather_kernel<<<grid, 256, 0, stream>>>(x, ws_mel, ws_idx, out, L);
}

// Round 5
// 77.259 us; speedup vs baseline: 1.1751x; 1.1751x over previous
//
#include <hip/hip_runtime.h>

#define BB 16
#define CC 256
#define TT 512
#define CCH 4              // channels per block
#define FT 1024            // frames per block (256 threads * 4)
#define NTH 256

// Fully fused LengthRegulator: each block recomputes the (cheap) duration scan
// for its batch, builds the frame->phoneme index table in LDS, stages its 4
// x-rows in LDS, then gathers + zero-fills with float4 stores.
__global__ __launch_bounds__(NTH) void lr_fused_kernel(
    const float* __restrict__ x,     // [B, C, T]
    const int* __restrict__ dur,     // [B, T]
    float* __restrict__ out,         // [B, C, L] ++ mel_len[B] (as float)
    int L)
{
    __shared__ int   lds_idx[FT];          // 4 KB
    __shared__ float lds_x[CCH * TT];      // 8 KB
    __shared__ int   wsum[NTH / 64];

    const int tid   = threadIdx.x;
    const int b     = blockIdx.z;
    const int c0    = blockIdx.y * CCH;
    const int fbase = blockIdx.x * FT;

    // init idx table (covers padding frames; must be a valid index)
    *(int4*)(lds_idx + tid * 4) = make_int4(0, 0, 0, 0);

    // ---- block-local inclusive scan of dur[b, :] (2 elems/thread) ----
    int2 dp = *(const int2*)(dur + b * TT + tid * 2);
    const int d0 = dp.x < 0 ? 0 : dp.x;
    const int d1 = dp.y < 0 ? 0 : dp.y;
    int v = d0 + d1;                        // pair sum
    #pragma unroll
    for (int off = 1; off < 64; off <<= 1) {
        int o = __shfl_up(v, off, 64);
        if ((tid & 63) >= off) v += o;
    }
    const int wid = tid >> 6;
    if ((tid & 63) == 63) wsum[wid] = v;

    // ---- stage x rows (4 rows = 2048 contiguous floats) while scan settles ----
    const float* __restrict__ xb = x + ((size_t)b * CC + c0) * TT;
    const float4 xv0 = *(const float4*)(xb + tid * 4);
    const float4 xv1 = *(const float4*)(xb + 1024 + tid * 4);
    *(float4*)(lds_x + tid * 4) = xv0;
    *(float4*)(lds_x + 1024 + tid * 4) = xv1;

    __syncthreads();

    int woff = 0, ml = 0;
    #pragma unroll
    for (int w = 0; w < NTH / 64; ++w) {
        const int s = wsum[w];
        if (w < wid) woff += s;
        ml += s;
    }
    const int cum1   = woff + v;            // inclusive cum of phoneme 2t+1
    const int cum0   = cum1 - d1;           // inclusive cum of phoneme 2t
    const int start0 = cum0 - d0;

    // scatter phoneme ids into lds_idx (only frames within this f-tile)
    const int fend = fbase + FT;
    {
        int lo = start0 > fbase ? start0 : fbase;
        int hi = cum0 < fend ? cum0 : fend;
        for (int f = lo; f < hi; ++f) lds_idx[f - fbase] = tid * 2;
        lo = cum0 > fbase ? cum0 : fbase;
        hi = cum1 < fend ? cum1 : fend;
        for (int f = lo; f < hi; ++f) lds_idx[f - fbase] = tid * 2 + 1;
    }
    __syncthreads();

    // ---- gather from LDS + zero-fill + store ----
    const int f0 = fbase + tid * 4;
    if (f0 < L) {
        const int4 id4 = *(const int4*)(lds_idx + tid * 4);
        const bool m0 = (f0 + 0) < ml;
        const bool m1 = (f0 + 1) < ml;
        const bool m2 = (f0 + 2) < ml;
        const bool m3 = (f0 + 3) < ml;
        float* __restrict__ ob = out + ((size_t)b * CC + c0) * (size_t)L + f0;
        if (((L & 3) == 0) && (f0 + 3 < L)) {
            #pragma unroll
            for (int cc = 0; cc < CCH; ++cc) {
                const float* __restrict__ xr = lds_x + cc * TT;
                float4 o;
                o.x = m0 ? xr[id4.x] : 0.0f;
                o.y = m1 ? xr[id4.y] : 0.0f;
                o.z = m2 ? xr[id4.z] : 0.0f;
                o.w = m3 ? xr[id4.w] : 0.0f;
                *(float4*)(ob + (size_t)cc * L) = o;
            }
        } else {
            const int nf = (L - f0) < 4 ? (L - f0) : 4;
            for (int cc = 0; cc < CCH; ++cc) {
                const float* __restrict__ xr = lds_x + cc * TT;
                for (int j = 0; j < nf; ++j) {
                    const int f = f0 + j;
                    const int id = lds_idx[tid * 4 + j];
                    ob[(size_t)cc * L + j] = (f < ml) ? xr[id] : 0.0f;
                }
            }
        }
    }

    // mel_len (as float32) — one block per batch writes it
    if (fbase == 0 && blockIdx.y == 0 && tid == 0)
        out[(size_t)BB * CC * L + b] = (float)ml;
}

extern "C" void kernel_launch(void* const* d_in, const int* in_sizes, int n_in,
                              void* d_out, int out_size, void* d_ws, size_t ws_size,
                              hipStream_t stream)
{
    const float* x = (const float*)d_in[0];
    const int* dur = (const int*)d_in[1];
    float* out     = (float*)d_out;

    // out = [B, C, L] floats ++ mel_len[B]  =>  L = (out_size - B) / (B*C)
    const int L = (out_size - BB) / (BB * CC);

    dim3 grid((L + FT - 1) / FT, CC / CCH, BB);
    lr_fused_kernel<<<grid, NTH, 0, stream>>>(x, dur, out, L);
}